// Round 10
// baseline (649.210 us; speedup 1.0000x reference)
//
#include <hip/hip_runtime.h>
#include <math.h>

// Problem constants (B=8, C=128, H=W=48 -> N=2304, E=6C=768), fp32 in/out.
constexpr int kB   = 8;
constexpr int kC   = 128;
constexpr int kN   = 2304;   // 48*48
constexpr int kE   = 768;
constexpr int kQKV = kC + kC + kE;  // 1024 fused projection rows

// Shared tiling: 128x128 block tile, K-chunk 32, 256 threads.
constexpr int TILE = 128;
constexpr int BK   = 32;
constexpr int TPAD = 132;  // fp32 path LDS row pad (words)
constexpr int KPAD = 40;   // bf16 path LDS row stride in ushort (80 B)

#define SCALE 0.08838834764831845f  // 1/sqrt(128)

typedef float f32x4 __attribute__((ext_vector_type(4)));
typedef short s16x8 __attribute__((ext_vector_type(8)));  // 8 bf16 bit-patterns
typedef short s16x4 __attribute__((ext_vector_type(4)));  // 4 bf16 bit-patterns

// ======================= fp32 vector-GEMM machinery =======================
// (verbatim from the audited pipeline; used by the qkv kernel)

__device__ __forceinline__ void load_direct(const float* __restrict__ g, int ld,
                                            int k0, int t0, float (*s)[TPAD]) {
  const int tid = threadIdx.x;
  const int c   = (tid & 31) * 4;
  const int r0  = tid >> 5;
#pragma unroll
  for (int rr = 0; rr < 4; ++rr) {
    const int k = r0 + rr * 8;
    const float4 v = *(const float4*)&g[(size_t)(k0 + k) * ld + t0 + c];
    *(float4*)&s[k][c] = v;
  }
}

__device__ __forceinline__ void load_trans(const float* __restrict__ g, int ld,
                                           int k0, int t0, float (*s)[TPAD]) {
  const int tid = threadIdx.x;
  const int kc  = (tid & 7) * 4;  // k offset, float4 along contiguous K
  const int r0  = tid >> 3;       // 0..31 (t row)
#pragma unroll
  for (int rr = 0; rr < 4; ++rr) {
    const int t = r0 + rr * 32;
    const float4 v = *(const float4*)&g[(size_t)(t0 + t) * ld + k0 + kc];
    s[kc + 0][t] = v.x;
    s[kc + 1][t] = v.y;
    s[kc + 2][t] = v.z;
    s[kc + 3][t] = v.w;
  }
}

__device__ __forceinline__ void mm_core(const float (*sA)[TPAD], const float (*sB)[TPAD],
                                        int ty, int tx, float acc[2][2][4][4]) {
#pragma unroll
  for (int kk = 0; kk < BK; ++kk) {
    const float4 a0 = *(const float4*)&sA[kk][ty * 4];
    const float4 a1 = *(const float4*)&sA[kk][64 + ty * 4];
    const float4 b0 = *(const float4*)&sB[kk][tx * 4];
    const float4 b1 = *(const float4*)&sB[kk][64 + tx * 4];
    const float a[2][4] = {{a0.x, a0.y, a0.z, a0.w}, {a1.x, a1.y, a1.z, a1.w}};
    const float b[2][4] = {{b0.x, b0.y, b0.z, b0.w}, {b1.x, b1.y, b1.z, b1.w}};
#pragma unroll
    for (int p = 0; p < 2; ++p)
#pragma unroll
      for (int q = 0; q < 2; ++q)
#pragma unroll
        for (int i = 0; i < 4; ++i)
#pragma unroll
          for (int j = 0; j < 4; ++j)
            acc[p][q][i][j] += a[p][i] * b[q][j];
  }
}

// ======================= split-bf16 MFMA machinery ========================
// fp32 x = hi(bf16) + lo(bf16) + eps, eps ~ 2^-17 relative: hi = RNE(x),
// r = x - hi is EXACT in fp32, lo = RNE(r). D = Ah*Bh + Ah*Bl + Al*Bh via
// 3 chained MFMAs -> fp32-grade accuracy on the unknown harness threshold.
//
// LDS tiles: [t][k] ushort bf16-bits, row stride KPAD=40 (80 B = 5x16 B,
// so every row base stays 16-B aligned). Element (t,k) stored at column
// k ^ (((t>>2)&3)<<3) (XOR on k-bits 3..4) to spread staged-write bank
// collisions; fragment reads undo the same XOR, so each lane's 8-wide
// k-slice stays one aligned 16 B ds_read.
//
// Fragment k-convention: lane's elements e=0..7 hold k = 8*(lane>>4)+e.
// A and B use the SAME convention, so any hardware (lane-group,e)->k map
// yields a correct dot product (k-permutation invariance). A-fragment row
// and B-fragment col = lane&15. D: col=lane&15, row=4*(lane>>4)+reg [m89].

__device__ __forceinline__ void split_bf16(float x, unsigned short& hi,
                                           unsigned short& lo) {
  const __bf16 h = (__bf16)x;           // RNE truncation to bf16
  const float  r = x - (float)h;        // exact residual
  const __bf16 l = (__bf16)r;
  hi = __builtin_bit_cast(unsigned short, h);
  lo = __builtin_bit_cast(unsigned short, l);
}

// Stage a [TILE] x [BK] tile from global layout [t][ld] (k contiguous).
__device__ __forceinline__ void stage_trans_split(
    const float* __restrict__ g, int ld, int k0, int t0,
    unsigned short (*sHi)[KPAD], unsigned short (*sLo)[KPAD]) {
  const int tid = threadIdx.x;
  const int kc  = (tid & 7) * 4;  // 0,4,...,28  (logical k base)
  const int r0  = tid >> 3;       // 0..31
#pragma unroll
  for (int rr = 0; rr < 4; ++rr) {
    const int t = r0 + rr * 32;
    const float4 v = *(const float4*)&g[(size_t)(t0 + t) * ld + k0 + kc];
    const int kz = kc ^ (((t >> 2) & 3) << 3);  // stays %4==0, <32
    unsigned short h[4], l[4];
    split_bf16(v.x, h[0], l[0]);
    split_bf16(v.y, h[1], l[1]);
    split_bf16(v.z, h[2], l[2]);
    split_bf16(v.w, h[3], l[3]);
    *(s16x4*)&sHi[t][kz] = (s16x4){(short)h[0], (short)h[1], (short)h[2], (short)h[3]};
    *(s16x4*)&sLo[t][kz] = (s16x4){(short)l[0], (short)l[1], (short)l[2], (short)l[3]};
  }
}

// Stage a [TILE] x [BK] tile from global layout [k][ld] (t contiguous).
__device__ __forceinline__ void stage_direct_split(
    const float* __restrict__ g, int ld, int k0, int t0,
    unsigned short (*sHi)[KPAD], unsigned short (*sLo)[KPAD]) {
  const int tid = threadIdx.x;
  const int c   = (tid & 31) * 4;  // t base, multiple of 4
  const int r0  = tid >> 5;        // 0..7 (k row)
  const int swz = ((c >> 2) & 3) << 3;  // same for t = c..c+3
#pragma unroll
  for (int rr = 0; rr < 4; ++rr) {
    const int k  = r0 + rr * 8;
    const int kz = k ^ swz;
    const float4 v = *(const float4*)&g[(size_t)(k0 + k) * ld + t0 + c];
    unsigned short h[4], l[4];
    split_bf16(v.x, h[0], l[0]);
    split_bf16(v.y, h[1], l[1]);
    split_bf16(v.z, h[2], l[2]);
    split_bf16(v.w, h[3], l[3]);
#pragma unroll
    for (int u = 0; u < 4; ++u) {
      sHi[c + u][kz] = h[u];
      sLo[c + u][kz] = l[u];
    }
  }
}

__device__ __forceinline__ s16x8 frag8(const unsigned short (*s)[KPAD], int t, int g) {
  const int col = 8 * (g ^ ((t >> 2) & 3));  // undo swizzle; 16B-aligned
  return *(const s16x8*)&s[t][col];
}

// One BK=32 k-chunk: wave (wr,wc) owns a 64x64 output quadrant as a 4x4
// grid of 16x16 MFMA tiles; 3 MFMAs per tile for the hi/lo split.
__device__ __forceinline__ void mfma_core_split(
    const unsigned short (*aHi)[KPAD], const unsigned short (*aLo)[KPAD],
    const unsigned short (*bHi)[KPAD], const unsigned short (*bLo)[KPAD],
    int wr, int wc, int lane, f32x4 acc[4][4]) {
  const int g  = lane >> 4;
  const int tr = lane & 15;
  s16x8 bh[4], bl[4];
#pragma unroll
  for (int ni = 0; ni < 4; ++ni) {
    const int t = wc * 64 + ni * 16 + tr;
    bh[ni] = frag8(bHi, t, g);
    bl[ni] = frag8(bLo, t, g);
  }
#pragma unroll
  for (int mi = 0; mi < 4; ++mi) {
    const int t = wr * 64 + mi * 16 + tr;
    const s16x8 ah = frag8(aHi, t, g);
    const s16x8 al = frag8(aLo, t, g);
#pragma unroll
    for (int ni = 0; ni < 4; ++ni) {
      acc[mi][ni] = __builtin_amdgcn_mfma_f32_16x16x32_bf16(ah, bh[ni], acc[mi][ni], 0, 0, 0);
      acc[mi][ni] = __builtin_amdgcn_mfma_f32_16x16x32_bf16(ah, bl[ni], acc[mi][ni], 0, 0, 0);
      acc[mi][ni] = __builtin_amdgcn_mfma_f32_16x16x32_bf16(al, bh[ni], acc[mi][ni], 0, 0, 0);
    }
  }
}

// ---------------------------------------------------------------------------
// Kernel 1 (fp32): fused QKV projection (fully batched).
// qkv[b][o][n] = sum_c Wcat[o][c] * x[b][c][n] + bcat[o]; K = c = 128.
// ---------------------------------------------------------------------------
__global__ __launch_bounds__(256) void qkv_kernel(
    const float* __restrict__ x,
    const float* __restrict__ wq, const float* __restrict__ bq,
    const float* __restrict__ wk, const float* __restrict__ bk,
    const float* __restrict__ wv, const float* __restrict__ bv,
    float* __restrict__ qkv)
{
  __shared__ float sA[BK][TPAD];  // [c][o] (weights, transposed)
  __shared__ float sB[BK][TPAD];  // [c][n] (x, direct)
  const int b   = blockIdx.z;
  const int o0  = blockIdx.y * TILE;
  const int n0  = blockIdx.x * TILE;
  const int tid = threadIdx.x;
  const int tx  = tid & 15, ty = tid >> 4;
  float acc[2][2][4][4] = {};
  const float* xb = x + (size_t)b * kC * kN;

  const float* wsrc;
  const float* bsrc;
  int orow0;
  if (o0 < kC)           { wsrc = wq; bsrc = bq; orow0 = o0; }
  else if (o0 < 2 * kC)  { wsrc = wk; bsrc = bk; orow0 = o0 - kC; }
  else                   { wsrc = wv; bsrc = bv; orow0 = o0 - 2 * kC; }

  for (int k0 = 0; k0 < kC; k0 += BK) {
    load_trans(wsrc + (size_t)orow0 * kC, kC, k0, 0, sA);
    load_direct(xb, kN, k0, n0, sB);
    __syncthreads();
    mm_core(sA, sB, ty, tx, acc);
    __syncthreads();
  }

  float* ob = qkv + (size_t)b * kQKV * kN;
#pragma unroll
  for (int p = 0; p < 2; ++p)
#pragma unroll
    for (int i = 0; i < 4; ++i) {
      const int t    = p * 64 + ty * 4 + i;
      const int o    = o0 + t;
      const float bias = bsrc[orow0 + t];
#pragma unroll
      for (int q = 0; q < 2; ++q) {
        float4 r;
        r.x = acc[p][q][i][0] + bias;
        r.y = acc[p][q][i][1] + bias;
        r.z = acc[p][q][i][2] + bias;
        r.w = acc[p][q][i][3] + bias;
        *(float4*)&ob[(size_t)o * kN + n0 + q * 64 + tx * 4] = r;
      }
    }
}

// ---------------------------------------------------------------------------
// Kernel 2 (split-bf16 MFMA): scores_slab[z][n][m] = SCALE*sum_c q*k for
// batch b0+z. K = c = 128. Staged DIRECT split tiles.
// ---------------------------------------------------------------------------
__global__ __launch_bounds__(256) void scores_mfma_kernel(
    const float* __restrict__ qkv, float* __restrict__ scores_slab, int b0)
{
  __shared__ unsigned short sAh[TILE][KPAD], sAl[TILE][KPAD];  // q: [t=n][k=c]
  __shared__ unsigned short sBh[TILE][KPAD], sBl[TILE][KPAD];  // k: [t=m][k=c]
  const int bz   = blockIdx.z;
  const int n0   = blockIdx.y * TILE;
  const int m0   = blockIdx.x * TILE;
  const int tid  = threadIdx.x;
  const int lane = tid & 63;
  const int wid  = tid >> 6;
  const int wr   = wid >> 1, wc = wid & 1;
  const float* qb = qkv + (size_t)(b0 + bz) * kQKV * kN;  // rows [0,128)
  const float* kb = qb + (size_t)kC * kN;                 // rows [128,256)

  f32x4 acc[4][4];
#pragma unroll
  for (int mi = 0; mi < 4; ++mi)
#pragma unroll
    for (int ni = 0; ni < 4; ++ni) acc[mi][ni] = (f32x4)(0.0f);

  for (int k0 = 0; k0 < kC; k0 += BK) {
    stage_direct_split(qb, kN, k0, n0, sAh, sAl);
    stage_direct_split(kb, kN, k0, m0, sBh, sBl);
    __syncthreads();
    mfma_core_split(sAh, sAl, sBh, sBl, wr, wc, lane, acc);
    __syncthreads();
  }

  float* sb = scores_slab + (size_t)bz * kN * kN;
  const int g = lane >> 4, c16 = lane & 15;
#pragma unroll
  for (int mi = 0; mi < 4; ++mi)
#pragma unroll
    for (int ni = 0; ni < 4; ++ni) {
      const int n = n0 + wr * 64 + mi * 16 + 4 * g;   // + j
      const int m = m0 + wc * 64 + ni * 16 + c16;
#pragma unroll
      for (int j = 0; j < 4; ++j)
        sb[(size_t)(n + j) * kN + m] = acc[mi][ni][j] * SCALE;
    }
}

// ---------------------------------------------------------------------------
// Kernel 3 (fp32): row-wise softmax over m (2304 = 9*256), in place on slab.
// ---------------------------------------------------------------------------
__global__ __launch_bounds__(256) void softmax_kernel(float* __restrict__ scores)
{
  const size_t row = blockIdx.x;  // over G*kN rows of the slab
  float* p = scores + row * kN;
  const int tid = threadIdx.x;
  float v[9];
  float m = -3.0e38f;
#pragma unroll
  for (int i = 0; i < 9; ++i) {
    v[i] = p[tid + i * 256];
    m = fmaxf(m, v[i]);
  }
#pragma unroll
  for (int off = 32; off >= 1; off >>= 1) m = fmaxf(m, __shfl_down(m, off));
  __shared__ float redm[4], reds[4];
  if ((tid & 63) == 0) redm[tid >> 6] = m;
  __syncthreads();
  m = fmaxf(fmaxf(redm[0], redm[1]), fmaxf(redm[2], redm[3]));
  float s = 0.f;
#pragma unroll
  for (int i = 0; i < 9; ++i) {
    v[i] = expf(v[i] - m);
    s += v[i];
  }
#pragma unroll
  for (int off = 32; off >= 1; off >>= 1) s += __shfl_down(s, off);
  if ((tid & 63) == 0) reds[tid >> 6] = s;
  __syncthreads();
  s = (reds[0] + reds[1]) + (reds[2] + reds[3]);
  const float inv = 1.f / s;
#pragma unroll
  for (int i = 0; i < 9; ++i) p[tid + i * 256] = v[i] * inv;
}

// ---------------------------------------------------------------------------
// Kernel 4 (split-bf16 MFMA): aout[b0+z][n][e] = sum_m attn_slab[z]*v.
// K = m = 2304. Staged TRANS split tiles.
// ---------------------------------------------------------------------------
__global__ __launch_bounds__(256) void av_mfma_kernel(
    const float* __restrict__ attn_slab, const float* __restrict__ qkv,
    float* __restrict__ aout, int b0)
{
  __shared__ unsigned short sAh[TILE][KPAD], sAl[TILE][KPAD];  // attn: [t=n][k=m]
  __shared__ unsigned short sBh[TILE][KPAD], sBl[TILE][KPAD];  // v:    [t=e][k=m]
  const int bz   = blockIdx.z;
  const int b    = b0 + bz;
  const int n0   = blockIdx.y * TILE;
  const int e0   = blockIdx.x * TILE;
  const int tid  = threadIdx.x;
  const int lane = tid & 63;
  const int wid  = tid >> 6;
  const int wr   = wid >> 1, wc = wid & 1;
  const float* ab = attn_slab + (size_t)bz * kN * kN;
  const float* vb = qkv + (size_t)b * kQKV * kN + (size_t)(2 * kC) * kN;

  f32x4 acc[4][4];
#pragma unroll
  for (int mi = 0; mi < 4; ++mi)
#pragma unroll
    for (int ni = 0; ni < 4; ++ni) acc[mi][ni] = (f32x4)(0.0f);

  for (int k0 = 0; k0 < kN; k0 += BK) {
    stage_trans_split(ab, kN, k0, n0, sAh, sAl);
    stage_trans_split(vb, kN, k0, e0, sBh, sBl);
    __syncthreads();
    mfma_core_split(sAh, sAl, sBh, sBl, wr, wc, lane, acc);
    __syncthreads();
  }

  const int g = lane >> 4, c16 = lane & 15;
#pragma unroll
  for (int mi = 0; mi < 4; ++mi)
#pragma unroll
    for (int ni = 0; ni < 4; ++ni) {
      const int n = n0 + wr * 64 + mi * 16 + 4 * g;        // + j
      const int e = e0 + wc * 64 + ni * 16 + c16;
#pragma unroll
      for (int j = 0; j < 4; ++j)
        aout[((size_t)b * kN + n + j) * kE + e] = acc[mi][ni][j];
    }
}

// ---------------------------------------------------------------------------
// Kernel 5 (split-bf16 MFMA): out[b][o][n] = sum_e wo[o][e]*aout[b][n][e]+bo.
// K = e = 768. Fully batched. Staged TRANS split tiles.
// ---------------------------------------------------------------------------
__global__ __launch_bounds__(256) void proj_mfma_kernel(
    const float* __restrict__ wo, const float* __restrict__ bo,
    const float* __restrict__ aout, float* __restrict__ out)
{
  __shared__ unsigned short sAh[TILE][KPAD], sAl[TILE][KPAD];  // wo:   [t=o][k=e]
  __shared__ unsigned short sBh[TILE][KPAD], sBl[TILE][KPAD];  // aout: [t=n][k=e]
  const int b    = blockIdx.z;
  const int o0   = blockIdx.y * TILE;
  const int n0   = blockIdx.x * TILE;
  const int tid  = threadIdx.x;
  const int lane = tid & 63;
  const int wid  = tid >> 6;
  const int wr   = wid >> 1, wc = wid & 1;
  const float* ob = aout + (size_t)b * kN * kE;

  f32x4 acc[4][4];
#pragma unroll
  for (int mi = 0; mi < 4; ++mi)
#pragma unroll
    for (int ni = 0; ni < 4; ++ni) acc[mi][ni] = (f32x4)(0.0f);

  for (int k0 = 0; k0 < kE; k0 += BK) {
    stage_trans_split(wo, kE, k0, o0, sAh, sAl);
    stage_trans_split(ob, kE, k0, n0, sBh, sBl);
    __syncthreads();
    mfma_core_split(sAh, sAl, sBh, sBl, wr, wc, lane, acc);
    __syncthreads();
  }

  const int g = lane >> 4, c16 = lane & 15;
#pragma unroll
  for (int mi = 0; mi < 4; ++mi)
#pragma unroll
    for (int j = 0; j < 4; ++j) {
      const int o = o0 + wr * 64 + mi * 16 + 4 * g + j;
      const float bias = bo[o];
#pragma unroll
      for (int ni = 0; ni < 4; ++ni) {
        const int n = n0 + wc * 64 + ni * 16 + c16;
        out[((size_t)b * kE + o) * kN + n] = acc[mi][ni][j] + bias;
      }
    }
}

// ---------------------------------------------------------------------------
extern "C" void kernel_launch(void* const* d_in, const int* in_sizes, int n_in,
                              void* d_out, int out_size, void* d_ws, size_t ws_size,
                              hipStream_t stream) {
  const float* x  = (const float*)d_in[0];
  const float* wq = (const float*)d_in[1];
  const float* bq = (const float*)d_in[2];
  const float* wk = (const float*)d_in[3];
  const float* bk = (const float*)d_in[4];
  const float* wv = (const float*)d_in[5];
  const float* bv = (const float*)d_in[6];
  const float* wo = (const float*)d_in[7];
  const float* bo = (const float*)d_in[8];
  float* out = (float*)d_out;

  // Workspace layout (floats): qkv | scores_slab(G batches) | aout.
  // G chosen as the largest group whose footprint fits ws_size; ws_size is
  // constant across calls, so the launch sequence is identical every call
  // (graph-capture safe).
  const size_t qkvN   = (size_t)kB * kQKV * kN;   // 18,874,368 f (75.5 MB)
  const size_t slab1  = (size_t)kN * kN;          //  5,308,416 f (21.2 MB/batch)
  const size_t aoutN  = (size_t)kB * kN * kE;     // 14,155,776 f (56.6 MB)
  const size_t baseB  = (qkvN + aoutN) * 4;
  int G = 1;
  if      (ws_size >= baseB + 8 * slab1 * 4) G = 8;   // 302.0 MB
  else if (ws_size >= baseB + 4 * slab1 * 4) G = 4;   // 217.1 MB
  else if (ws_size >= baseB + 2 * slab1 * 4) G = 2;   // 174.6 MB
  //      else G = 1                                  // 153.4 MB

  float* qkv   = (float*)d_ws;
  float* sslab = qkv + qkvN;
  float* aout  = sslab + (size_t)G * slab1;

  dim3 blk(256);
  qkv_kernel<<<dim3(kN / TILE, kQKV / TILE, kB), blk, 0, stream>>>(
      x, wq, bq, wk, bk, wv, bv, qkv);
  for (int b0 = 0; b0 < kB; b0 += G) {
    scores_mfma_kernel<<<dim3(kN / TILE, kN / TILE, G), blk, 0, stream>>>(
        qkv, sslab, b0);
    softmax_kernel<<<dim3(G * kN), blk, 0, stream>>>(sslab);
    av_mfma_kernel<<<dim3(kE / TILE, kN / TILE, G), blk, 0, stream>>>(
        sslab, qkv, aout, b0);
  }
  proj_mfma_kernel<<<dim3(kN / TILE, kE / TILE, kB), blk, 0, stream>>>(
      wo, bo, aout, out);
}